// Round 11
// baseline (137.881 us; speedup 1.0000x reference)
//
#include <hip/hip_runtime.h>
#include <hip/hip_bf16.h>
#include <math.h>

#define NN 262144
#define QQ 256
#define PS 80
#define BB 4096
#define NSLOT 4
#define RT 64             // rows per strip
#define NITER 8           // K tiles of 32
#define SMEM_BYTES 30720  // res_u (20480) + res_v (10240); NO staging LDS

typedef _Float16 f16x8 __attribute__((ext_vector_type(8)));
typedef float f32x4  __attribute__((ext_vector_type(4)));

__device__ inline unsigned short f16b(float f) {
  return __builtin_bit_cast(unsigned short, (_Float16)f);
}
__device__ inline float f16tof(unsigned short u) {
  return (float)__builtin_bit_cast(_Float16, u);
}

// ---------------------------------------------------------------------------
// Kernel 0: B = [beta_u | beta_z] -> fp16 in frag-coalesced layout:
// bFlat[kt][kg][c][j]  (kt<8, kg<4, c<160, j<8), elem k = kt*32+kg*8+j.
// A wave's B-frag read (lanes: kg=lane>>4, c=base+lane&15) is then 4
// contiguous 256B segments -> perfectly coalesced, L2-resident (160 KB).
// ---------------------------------------------------------------------------
__global__ void bprep_k(const float* __restrict__ bu, const float* __restrict__ bz,
                        unsigned short* __restrict__ bFlat) {
  int gid = blockIdx.x * 256 + threadIdx.x;   // 8*4*160 = 5120 units
  if (gid >= 5120) return;
  int kt  = gid / 640;
  int rem = gid - kt * 640;
  int kg  = rem / 160;
  int c   = rem - kg * 160;
  unsigned short* dst = bFlat + (size_t)gid * 8;
  int kbase = kt * 32 + kg * 8;
#pragma unroll
  for (int j = 0; j < 8; ++j) {
    int k = kbase + j;
    float v = (c < PS) ? bu[k * PS + c] : bz[k * PS + (c - PS)];
    dst[j] = f16b(v);
  }
}

// ---------------------------------------------------------------------------
// Kernel 1: segment boundaries (seg_ids sorted, int32 from harness).
// ---------------------------------------------------------------------------
__global__ void seg_bounds_k(const int* __restrict__ seg, int* __restrict__ segstart) {
  int b = blockIdx.x * blockDim.x + threadIdx.x;
  if (b > BB) return;
  if (b == BB) { segstart[BB] = NN; return; }
  int lo = 0, hi = NN;
  while (lo < hi) {
    int mid = (lo + hi) >> 1;
    if (seg[mid] < b) lo = mid + 1; else hi = mid;
  }
  segstart[b] = lo;
}

// ---------------------------------------------------------------------------
// Kernel 2: FUSED fp16 MFMA GEMM (64x160x256 per block) with ZERO-LDS,
// ZERO-BARRIER K-loop + in-LDS segmented online softmax-pool.
// 256 thr = 4 waves (2 row x 2 col), wave tile 32r x 80c (acc 2x5).
// A: global->reg direct. Lane reads x[rs+wr+m*16+(lane&15)][kt*32+(lane>>4)*8
//    ..+8] as 2 float4 -> exactly the MFMA A-frag; per-wave = 16 rows x 128B
//    coalesced segments. Ping-pong depth-2 prefetch (issued 2 iters ahead).
// B: global->reg direct from bFlat (L2-resident), depth-1 prefetch.
// No ds_write/ds_read/syncthreads in the loop -> waves fully independent;
// latency hidden by reg prefetch + wave multiplexing (fixes the r7-r10
// barrier-chain stall that counted-vmcnt couldn't).
// MFMA 16x16x32_f16: A row=lane&15, k=8*(lane>>4)+j; D col=lane&15,
// row=(lane>>4)*4+reg  [verified r3-r10].
// ---------------------------------------------------------------------------
__global__ __launch_bounds__(256, 3) void fused_k(
    const float* __restrict__ x, const unsigned short* __restrict__ bFlat,
    const int* __restrict__ seg, const int* __restrict__ segstart,
    float* __restrict__ pm, float* __restrict__ pse, float* __restrict__ pst) {
  __shared__ __align__(16) char smem[SMEM_BYTES];
  const int tid  = threadIdx.x;
  const int wid  = tid >> 6;
  const int lane = tid & 63;
  const int rs   = blockIdx.x * RT;

  const int wr   = (wid & 1) * 32;   // wave row offset
  const int cw   = wid >> 1;         // 0 -> u cols, 1 -> tz cols
  const int lrow = lane & 15;
  const int lk16 = lane >> 4;

  // per-lane global bases
  const float* xA = x + (size_t)(rs + wr + lrow) * QQ + lk16 * 8;
  const unsigned short* bA = bFlat + ((size_t)lk16 * 160 + cw * 80 + lrow) * 8;

  float4 xr[2][4];   // [slot][2*m + half] : A k-window 32B per m
  f16x8  br[2][5];   // [slot][n]

#define LOADA(s_, t_) do {                                                    \
    xr[s_][0] = *reinterpret_cast<const float4*>(xA + (t_) * 32);             \
    xr[s_][1] = *reinterpret_cast<const float4*>(xA + (t_) * 32 + 4);         \
    xr[s_][2] = *reinterpret_cast<const float4*>(xA + 16 * QQ + (t_) * 32);   \
    xr[s_][3] = *reinterpret_cast<const float4*>(xA + 16 * QQ + (t_) * 32 + 4); \
  } while (0)

#define LOADB(s_, t_) do {                                                    \
    _Pragma("unroll")                                                         \
    for (int n_ = 0; n_ < 5; ++n_)                                            \
      br[s_][n_] = *reinterpret_cast<const f16x8*>(bA + (t_) * 5120 + n_ * 128); \
  } while (0)

  f32x4 acc[2][5];
#pragma unroll
  for (int m = 0; m < 2; ++m)
#pragma unroll
    for (int n = 0; n < 5; ++n) acc[m][n] = (f32x4){0.f, 0.f, 0.f, 0.f};

  // prologue: A for tiles 0,1 in flight; B for tile 0 in flight
  LOADA(0, 0);
  LOADA(1, 1);
  LOADB(0, 0);

#pragma unroll
  for (int t = 0; t < NITER; ++t) {
    const int s = t & 1;
    // convert A(t) f32 -> f16 frags (waits on the load issued 2 iters ago;
    // frees xr[s] so the A(t+2) issue below can safely retarget it)
    f16x8 af[2];
#pragma unroll
    for (int m = 0; m < 2; ++m) {
      float4 u0 = xr[s][2 * m], u1 = xr[s][2 * m + 1];
      af[m][0] = (_Float16)u0.x; af[m][1] = (_Float16)u0.y;
      af[m][2] = (_Float16)u0.z; af[m][3] = (_Float16)u0.w;
      af[m][4] = (_Float16)u1.x; af[m][5] = (_Float16)u1.y;
      af[m][6] = (_Float16)u1.z; af[m][7] = (_Float16)u1.w;
    }
    if (t < NITER - 2) LOADA(s, t + 2);
    if (t < NITER - 1) LOADB((t + 1) & 1, t + 1);

    __builtin_amdgcn_s_setprio(1);
#pragma unroll
    for (int n = 0; n < 5; ++n) {
      acc[0][n] = __builtin_amdgcn_mfma_f32_16x16x32_f16(af[0], br[s][n], acc[0][n], 0, 0, 0);
      acc[1][n] = __builtin_amdgcn_mfma_f32_16x16x32_f16(af[1], br[s][n], acc[1][n], 0, 0, 0);
    }
    __builtin_amdgcn_s_setprio(0);
  }
#undef LOADA
#undef LOADB

  // ---- result tile to LDS (u f32, t fp16)
  float* res_u          = reinterpret_cast<float*>(smem);                  // 20480
  unsigned short* res_v = reinterpret_cast<unsigned short*>(smem + 20480); // 10240
#pragma unroll
  for (int m = 0; m < 2; ++m)
#pragma unroll
    for (int n = 0; n < 5; ++n)
#pragma unroll
      for (int rr = 0; rr < 4; ++rr) {
        int row = wr + m * 16 + lk16 * 4 + rr;
        int col = n * 16 + lrow;
        if (cw == 0) res_u[row * 80 + col] = acc[m][n][rr];
        else         res_v[row * 80 + col] = f16b(acc[m][n][rr]);
      }
  __syncthreads();

  // ---- segmented online softmax-pool over this 64-row strip
  int b0 = seg[rs];
  int b1 = seg[rs + RT - 1];
  int nu = (b1 - b0 + 1) * PS;
  for (int u = tid; u < nu; u += 256) {
    int bag = b0 + u / PS;
    int c   = u % PS;
    int sb  = segstart[bag];
    int lo  = max(sb, rs) - rs;
    int hi  = min(segstart[bag + 1], rs + RT) - rs;
    float m_ = -3.4e38f, se = 0.f, st = 0.f;
    for (int r = lo; r < hi; ++r) {
      float v  = res_u[r * 80 + c];
      float tv = f16tof(res_v[r * 80 + c]);
      float nm = fmaxf(m_, v);
      float sc = __expf(m_ - nm);
      float ee = __expf(v - nm);
      se = se * sc + ee;
      st = st * sc + ee * tv;
      m_ = nm;
    }
    int slot = blockIdx.x - (sb >> 6);
    size_t p = ((size_t)bag * NSLOT + slot) * PS + c;
    pm[p] = m_; pse[p] = se; pst[p] = st;
  }
}

// ---------------------------------------------------------------------------
// Kernel 3: merge partial slots per (bag,col) -> zb (= d_out).
// ---------------------------------------------------------------------------
__global__ __launch_bounds__(256) void combine_k(
    const int* __restrict__ segstart,
    const float* __restrict__ pm, const float* __restrict__ pse,
    const float* __restrict__ pst, float* __restrict__ zb) {
  int i = blockIdx.x * 256 + threadIdx.x;   // BB*PS
  if (i >= BB * PS) return;
  int bag = i / PS, c = i % PS;
  int sb = segstart[bag], eb = segstart[bag + 1];
  float z = 0.f;
  if (eb > sb) {
    int ns = ((eb - 1) >> 6) - (sb >> 6) + 1;
    ns = min(ns, NSLOT);
    float m = -3.4e38f, se = 0.f, st = 0.f;
    for (int s = 0; s < ns; ++s) {
      size_t p = ((size_t)bag * NSLOT + s) * PS + c;
      float m2 = pm[p], se2 = pse[p], st2 = pst[p];
      float nm = fmaxf(m, m2);
      float s1 = __expf(m - nm);
      float s2 = __expf(m2 - nm);
      se = se * s1 + se2 * s2;
      st = st * s1 + st2 * s2;
      m = nm;
    }
    z = st / se;
  }
  zb[i] = z;
}

// ---------------------------------------------------------------------------
// Kernel 4: per-column stats + b-scale, IN PLACE on d_out.
// ---------------------------------------------------------------------------
__device__ inline float wave_sum(float v) {
#pragma unroll
  for (int o = 32; o > 0; o >>= 1) v += __shfl_down(v, o, 64);
  return v;
}

__global__ __launch_bounds__(256) void finalize_k(
    const float* __restrict__ bz, float* __restrict__ zb_out) {
  const int c = blockIdx.x;
  const int t = threadIdx.x;

  float bvz = bz[t * PS + c];
  float bsq = bvz * bvz;

  float s = 0.f, ss = 0.f;
  for (int b = t; b < BB; b += 256) {
    float z = zb_out[b * PS + c];
    s += z;
    ss += z * z;
  }

  __shared__ float w0[4], w1[4], w2[4];
  float a0 = wave_sum(bsq);
  float a1 = wave_sum(s);
  float a2 = wave_sum(ss);
  int wid = t >> 6, lane = t & 63;
  if (lane == 0) { w0[wid] = a0; w1[wid] = a1; w2[wid] = a2; }
  __syncthreads();

  __shared__ float sh[3];
  if (t == 0) {
    float B0 = w0[0] + w0[1] + w0[2] + w0[3];
    float S1 = w1[0] + w1[1] + w1[2] + w1[3];
    float S2 = w2[0] + w2[1] + w2[2] + w2[3];
    float bval = sqrtf(B0 / (float)QQ);
    float mean = S1 / (float)BB;
    float var = (S2 - (float)BB * mean * mean) / (float)(BB - 1);
    float sd = sqrtf(fmaxf(var, 0.f));
    if (!(sd > 0.f) || sd != sd) sd = 1.f;
    sh[0] = bval; sh[1] = mean; sh[2] = sd;
  }
  __syncthreads();
  float bval = sh[0], mean = sh[1], sd = sh[2];
  for (int b = t; b < BB; b += 256) {
    zb_out[b * PS + c] = bval * (zb_out[b * PS + c] - mean) / sd;
  }
}

// ---------------------------------------------------------------------------
extern "C" void kernel_launch(void* const* d_in, const int* in_sizes, int n_in,
                              void* d_out, int out_size, void* d_ws, size_t ws_size,
                              hipStream_t stream) {
  const float* x   = (const float*)d_in[0];
  const float* bu  = (const float*)d_in[1];
  const float* bz  = (const float*)d_in[2];
  const int*   seg = (const int*)d_in[3];   // harness narrows int64 -> int32
  float* out = (float*)d_out;

  // workspace layout (bytes):
  //   [0,     16640)  segstart (4097 ints, padded)
  //   [16640, 98560)  bFlat: 8*4*160*8 fp16 = 81920
  //   [98560, ...)    pm / pse / pst: BB*NSLOT*PS floats each
  char* ws = (char*)d_ws;
  int* segstart         = (int*)ws;
  unsigned short* bFlat = (unsigned short*)(ws + 16640);
  size_t pn  = (size_t)BB * NSLOT * PS;
  float* pm  = (float*)(ws + 98560);
  float* pse = pm + pn;
  float* pst = pse + pn;

  bprep_k<<<20, 256, 0, stream>>>(bu, bz, bFlat);
  seg_bounds_k<<<(BB + 1 + 255) / 256, 256, 0, stream>>>(seg, segstart);
  fused_k<<<NN / RT, 256, 0, stream>>>(x, bFlat, seg, segstart, pm, pse, pst);
  combine_k<<<(BB * PS + 255) / 256, 256, 0, stream>>>(segstart, pm, pse, pst, out);
  finalize_k<<<PS, 256, 0, stream>>>(bz, out);
}

// Round 12
// 101.333 us; speedup vs baseline: 1.3607x; 1.3607x over previous
//
#include <hip/hip_runtime.h>
#include <hip/hip_bf16.h>
#include <math.h>

#define NN 262144
#define QQ 256
#define PS 80
#define BB 4096
#define NSLOT 4
#define RT 64             // rows per strip
#define NITER 8           // K tiles of 32
#define SMEM_BYTES 32768  // A-strip fp16 [8 kt][4 kg][64 row^swz][16B]; res union 30720

typedef _Float16 f16x8 __attribute__((ext_vector_type(8)));
typedef float f32x4  __attribute__((ext_vector_type(4)));

__device__ inline unsigned short f16b(float f) {
  return __builtin_bit_cast(unsigned short, (_Float16)f);
}
__device__ inline float f16tof(unsigned short u) {
  return (float)__builtin_bit_cast(_Float16, u);
}

// ---------------------------------------------------------------------------
// Kernel 0: B = [beta_u | beta_z] -> fp16 frag-coalesced bFlat[kt][kg][c][j]
// (kt<8, kg<4, c<160, j<8), elem k = kt*32+kg*8+j.  [validated r11]
// ---------------------------------------------------------------------------
__global__ void bprep_k(const float* __restrict__ bu, const float* __restrict__ bz,
                        unsigned short* __restrict__ bFlat) {
  int gid = blockIdx.x * 256 + threadIdx.x;   // 5120 units
  if (gid >= 5120) return;
  int kt  = gid / 640;
  int rem = gid - kt * 640;
  int kg  = rem / 160;
  int c   = rem - kg * 160;
  unsigned short* dst = bFlat + (size_t)gid * 8;
  int kbase = kt * 32 + kg * 8;
#pragma unroll
  for (int j = 0; j < 8; ++j) {
    int k = kbase + j;
    float v = (c < PS) ? bu[k * PS + c] : bz[k * PS + (c - PS)];
    dst[j] = f16b(v);
  }
}

// ---------------------------------------------------------------------------
// Kernel 1: segment boundaries (seg_ids sorted, int32 from harness).
// ---------------------------------------------------------------------------
__global__ void seg_bounds_k(const int* __restrict__ seg, int* __restrict__ segstart) {
  int b = blockIdx.x * blockDim.x + threadIdx.x;
  if (b > BB) return;
  if (b == BB) { segstart[BB] = NN; return; }
  int lo = 0, hi = NN;
  while (lo < hi) {
    int mid = (lo + hi) >> 1;
    if (seg[mid] < b) lo = mid + 1; else hi = mid;
  }
  segstart[b] = lo;
}

// ---------------------------------------------------------------------------
// Kernel 2: FUSED fp16 MFMA GEMM (64x160x256) + segmented softmax-pool.
// Phase 1 (staging): ALL 16 x-float4 loads issued up front per thread
//   (64KB/block in flight -> HBM streaming), cvt f32->fp16, 8 uint4
//   ds_writes into [kt][kg][row^(kg<<2)][16B] (conflict-free, r9 pattern).
//   ONE barrier.
// Phase 2 (K-loop, NO barriers): 8 unrolled iters of
//   {2 ds_read_b128 A-frags, 10 MFMA}; B global->reg from L2-resident bFlat
//   (depth-2 slots, each slot reloaded AFTER its MFMA cluster).
// Phase 3: barrier, result->LDS (res union), barrier, in-LDS pool.
// MFMA 16x16x32_f16: A row=lane&15, k=8*(lane>>4)+j; D col=lane&15,
// row=(lane>>4)*4+reg  [verified r3-r11].
// ---------------------------------------------------------------------------
__global__ __launch_bounds__(256, 4) void fused_k(
    const float* __restrict__ x, const unsigned short* __restrict__ bFlat,
    const int* __restrict__ seg, const int* __restrict__ segstart,
    float* __restrict__ pm, float* __restrict__ pse, float* __restrict__ pst) {
  __shared__ __align__(16) char smem[SMEM_BYTES];
  const int tid  = threadIdx.x;
  const int lane = tid & 63;
  const int wid  = tid >> 6;
  const int rs   = blockIdx.x * RT;

  const int wr   = (wid & 1) * 32;   // wave row offset
  const int cw   = wid >> 1;         // 0 -> u cols, 1 -> tz cols
  const int lrow = lane & 15;
  const int lk16 = lane >> 4;

  // ---------- Phase 1: stage whole x-strip (64 rows x 256 k) as fp16 ----------
  {
    const int ra = tid >> 2;         // 0..63
    const int kg = tid & 3;          // 0..3
    const float* xp = x + (size_t)(rs + ra) * QQ + kg * 8;
    float4 xs[16];
#pragma unroll
    for (int kt = 0; kt < NITER; ++kt) {
      xs[2 * kt]     = *reinterpret_cast<const float4*>(xp + kt * 32);
      xs[2 * kt + 1] = *reinterpret_cast<const float4*>(xp + kt * 32 + 4);
    }
    char* dst = smem + kg * 1024 + ((ra ^ (kg << 2)) * 16);
#pragma unroll
    for (int kt = 0; kt < NITER; ++kt) {
      float4 v0 = xs[2 * kt], v1 = xs[2 * kt + 1];
      unsigned short a0 = f16b(v0.x), a1 = f16b(v0.y), a2 = f16b(v0.z), a3 = f16b(v0.w);
      unsigned short a4 = f16b(v1.x), a5 = f16b(v1.y), a6 = f16b(v1.z), a7 = f16b(v1.w);
      uint4 w = make_uint4((unsigned)a0 | ((unsigned)a1 << 16),
                           (unsigned)a2 | ((unsigned)a3 << 16),
                           (unsigned)a4 | ((unsigned)a5 << 16),
                           (unsigned)a6 | ((unsigned)a7 << 16));
      *reinterpret_cast<uint4*>(dst + kt * 4096) = w;
    }
  }
  __syncthreads();

  // ---------- Phase 2: barrier-free K-loop ----------
  const unsigned short* bA = bFlat + ((size_t)lk16 * 160 + cw * 80 + lrow) * 8;
  const int aoff0 = lk16 * 1024 + (((wr + lrow)      ^ (lk16 << 2)) * 16);
  const int aoff1 = lk16 * 1024 + (((wr + 16 + lrow) ^ (lk16 << 2)) * 16);

  f16x8 br[2][5];
#define LOADB(s_, t_) do {                                                    \
    _Pragma("unroll")                                                         \
    for (int n_ = 0; n_ < 5; ++n_)                                            \
      br[s_][n_] = *reinterpret_cast<const f16x8*>(bA + (t_) * 5120 + n_ * 128); \
  } while (0)

  f32x4 acc[2][5];
#pragma unroll
  for (int m = 0; m < 2; ++m)
#pragma unroll
    for (int n = 0; n < 5; ++n) acc[m][n] = (f32x4){0.f, 0.f, 0.f, 0.f};

  LOADB(0, 0);
  LOADB(1, 1);

#pragma unroll
  for (int t = 0; t < NITER; ++t) {
    const int s = t & 1;
    f16x8 a0 = *reinterpret_cast<const f16x8*>(smem + t * 4096 + aoff0);
    f16x8 a1 = *reinterpret_cast<const f16x8*>(smem + t * 4096 + aoff1);
    __builtin_amdgcn_s_setprio(1);
#pragma unroll
    for (int n = 0; n < 5; ++n) {
      acc[0][n] = __builtin_amdgcn_mfma_f32_16x16x32_f16(a0, br[s][n], acc[0][n], 0, 0, 0);
      acc[1][n] = __builtin_amdgcn_mfma_f32_16x16x32_f16(a1, br[s][n], acc[1][n], 0, 0, 0);
    }
    __builtin_amdgcn_s_setprio(0);
    if (t < NITER - 2) LOADB(s, t + 2);   // reload slot AFTER its MFMA cluster
  }
#undef LOADB

  // ---------- Phase 3: result tile -> LDS (res union), pool ----------
  __syncthreads();   // all A ds_reads done before staging area is overwritten
  float* res_u          = reinterpret_cast<float*>(smem);                  // 20480
  unsigned short* res_v = reinterpret_cast<unsigned short*>(smem + 20480); // 10240
#pragma unroll
  for (int m = 0; m < 2; ++m)
#pragma unroll
    for (int n = 0; n < 5; ++n)
#pragma unroll
      for (int rr = 0; rr < 4; ++rr) {
        int row = wr + m * 16 + lk16 * 4 + rr;
        int col = n * 16 + lrow;
        if (cw == 0) res_u[row * 80 + col] = acc[m][n][rr];
        else         res_v[row * 80 + col] = f16b(acc[m][n][rr]);
      }
  __syncthreads();

  // segmented online softmax-pool over this 64-row strip
  int b0 = seg[rs];
  int b1 = seg[rs + RT - 1];
  int nu = (b1 - b0 + 1) * PS;
  for (int u = tid; u < nu; u += 256) {
    int bag = b0 + u / PS;
    int c   = u % PS;
    int sb  = segstart[bag];
    int lo  = max(sb, rs) - rs;
    int hi  = min(segstart[bag + 1], rs + RT) - rs;
    float m_ = -3.4e38f, se = 0.f, st = 0.f;
    for (int r = lo; r < hi; ++r) {
      float v  = res_u[r * 80 + c];
      float tv = f16tof(res_v[r * 80 + c]);
      float nm = fmaxf(m_, v);
      float sc = __expf(m_ - nm);
      float ee = __expf(v - nm);
      se = se * sc + ee;
      st = st * sc + ee * tv;
      m_ = nm;
    }
    int slot = blockIdx.x - (sb >> 6);
    size_t p = ((size_t)bag * NSLOT + slot) * PS + c;
    pm[p] = m_; pse[p] = se; pst[p] = st;
  }
}

// ---------------------------------------------------------------------------
// Kernel 3: merge partial slots per (bag,col) -> zb (= d_out).
// ---------------------------------------------------------------------------
__global__ __launch_bounds__(256) void combine_k(
    const int* __restrict__ segstart,
    const float* __restrict__ pm, const float* __restrict__ pse,
    const float* __restrict__ pst, float* __restrict__ zb) {
  int i = blockIdx.x * 256 + threadIdx.x;   // BB*PS
  if (i >= BB * PS) return;
  int bag = i / PS, c = i % PS;
  int sb = segstart[bag], eb = segstart[bag + 1];
  float z = 0.f;
  if (eb > sb) {
    int ns = ((eb - 1) >> 6) - (sb >> 6) + 1;
    ns = min(ns, NSLOT);
    float m = -3.4e38f, se = 0.f, st = 0.f;
    for (int s = 0; s < ns; ++s) {
      size_t p = ((size_t)bag * NSLOT + s) * PS + c;
      float m2 = pm[p], se2 = pse[p], st2 = pst[p];
      float nm = fmaxf(m, m2);
      float s1 = __expf(m - nm);
      float s2 = __expf(m2 - nm);
      se = se * s1 + se2 * s2;
      st = st * s1 + st2 * s2;
      m = nm;
    }
    z = st / se;
  }
  zb[i] = z;
}

// ---------------------------------------------------------------------------
// Kernel 4: per-column stats + b-scale, IN PLACE on d_out.
// ---------------------------------------------------------------------------
__device__ inline float wave_sum(float v) {
#pragma unroll
  for (int o = 32; o > 0; o >>= 1) v += __shfl_down(v, o, 64);
  return v;
}

__global__ __launch_bounds__(256) void finalize_k(
    const float* __restrict__ bz, float* __restrict__ zb_out) {
  const int c = blockIdx.x;
  const int t = threadIdx.x;

  float bvz = bz[t * PS + c];
  float bsq = bvz * bvz;

  float s = 0.f, ss = 0.f;
  for (int b = t; b < BB; b += 256) {
    float z = zb_out[b * PS + c];
    s += z;
    ss += z * z;
  }

  __shared__ float w0[4], w1[4], w2[4];
  float a0 = wave_sum(bsq);
  float a1 = wave_sum(s);
  float a2 = wave_sum(ss);
  int wid = t >> 6, lane = t & 63;
  if (lane == 0) { w0[wid] = a0; w1[wid] = a1; w2[wid] = a2; }
  __syncthreads();

  __shared__ float sh[3];
  if (t == 0) {
    float B0 = w0[0] + w0[1] + w0[2] + w0[3];
    float S1 = w1[0] + w1[1] + w1[2] + w1[3];
    float S2 = w2[0] + w2[1] + w2[2] + w2[3];
    float bval = sqrtf(B0 / (float)QQ);
    float mean = S1 / (float)BB;
    float var = (S2 - (float)BB * mean * mean) / (float)(BB - 1);
    float sd = sqrtf(fmaxf(var, 0.f));
    if (!(sd > 0.f) || sd != sd) sd = 1.f;
    sh[0] = bval; sh[1] = mean; sh[2] = sd;
  }
  __syncthreads();
  float bval = sh[0], mean = sh[1], sd = sh[2];
  for (int b = t; b < BB; b += 256) {
    zb_out[b * PS + c] = bval * (zb_out[b * PS + c] - mean) / sd;
  }
}

// ---------------------------------------------------------------------------
extern "C" void kernel_launch(void* const* d_in, const int* in_sizes, int n_in,
                              void* d_out, int out_size, void* d_ws, size_t ws_size,
                              hipStream_t stream) {
  const float* x   = (const float*)d_in[0];
  const float* bu  = (const float*)d_in[1];
  const float* bz  = (const float*)d_in[2];
  const int*   seg = (const int*)d_in[3];   // harness narrows int64 -> int32
  float* out = (float*)d_out;

  // workspace layout (bytes):
  //   [0,     16640)  segstart (4097 ints, padded)
  //   [16640, 98560)  bFlat: 8*4*160*8 fp16 = 81920
  //   [98560, ...)    pm / pse / pst: BB*NSLOT*PS floats each
  char* ws = (char*)d_ws;
  int* segstart         = (int*)ws;
  unsigned short* bFlat = (unsigned short*)(ws + 16640);
  size_t pn  = (size_t)BB * NSLOT * PS;
  float* pm  = (float*)(ws + 98560);
  float* pse = pm + pn;
  float* pst = pse + pn;

  bprep_k<<<20, 256, 0, stream>>>(bu, bz, bFlat);
  seg_bounds_k<<<(BB + 1 + 255) / 256, 256, 0, stream>>>(seg, segstart);
  fused_k<<<NN / RT, 256, 0, stream>>>(x, bFlat, seg, segstart, pm, pse, pst);
  combine_k<<<(BB * PS + 255) / 256, 256, 0, stream>>>(segstart, pm, pse, pst, out);
  finalize_k<<<PS, 256, 0, stream>>>(bz, out);
}